// Round 24
// baseline (411.991 us; speedup 1.0000x reference)
//
#include <hip/hip_runtime.h>
#include <hip/hip_bf16.h>
#include <math.h>

#define T_STEPS 2048
#define B_SZ 16
#define D_SZ 1024
#define N_SZ 64
#define M_ROWS (T_STEPS * B_SZ)   // 32768
#define NOUT (4 * N_SZ)           // 256
#define U_BLK 8
#define NBLK (T_STEPS / U_BLK)    // 256
#define TSTR 17                   // transposed kn/q LDS row stride (floats)

typedef __attribute__((ext_vector_type(8))) short bf16x8;
typedef __attribute__((ext_vector_type(4))) float f32x4;

// ---------------------------------------------------------------------------
// DPP reduction (R4-R6 verified) — used by norm_gram only.
// ---------------------------------------------------------------------------
template <int CTRL, int RMASK, bool BC>
__device__ __forceinline__ float dpp_add(float v) {
  return v + __int_as_float(__builtin_amdgcn_update_dpp(
                 0, __float_as_int(v), CTRL, RMASK, 0xF, BC));
}
__device__ __forceinline__ float wave_red(float v) {
  v = dpp_add<0xB1, 0xF, true>(v);
  v = dpp_add<0x4E, 0xF, true>(v);
  v = dpp_add<0x141, 0xF, true>(v);
  v = dpp_add<0x140, 0xF, true>(v);
  v = dpp_add<0x142, 0xA, false>(v);
  v = dpp_add<0x143, 0xC, false>(v);
  return __int_as_float(__builtin_amdgcn_readlane(__float_as_int(v), 63));
}

// fp32 pair -> packed bf16x2 (RNE) via v_cvt_pk_bf16_f32.
__device__ __forceinline__ unsigned cvt2(float a, float b) {
  float2 f; f.x = a; f.y = b;
  __hip_bfloat162 h = __float22bfloat162_rn(f);
  return *reinterpret_cast<unsigned*>(&h);
}

// ---------------------------------------------------------------------------
// Kernel 0: W (fp32, 1 MB) -> Wb (bf16, 0.5 MB), once (R20-verified).
// ---------------------------------------------------------------------------
__global__ __launch_bounds__(256) void wcvt(const float* __restrict__ W,
                                            unsigned* __restrict__ Wb) {
  const size_t idx = ((size_t)blockIdx.x * 256 + threadIdx.x) * 4;
  const float4 f = *reinterpret_cast<const float4*>(&W[idx]);
  uint2 o;
  o.x = cvt2(f.x, f.y);
  o.y = cvt2(f.z, f.w);
  *reinterpret_cast<uint2*>(&Wb[idx >> 1]) = o;
}

// ---------------------------------------------------------------------------
// Kernel 1: proj = x @ W^T via bf16 MFMA, bf16 W (R20-verified best GEMM).
// ---------------------------------------------------------------------------
__global__ __launch_bounds__(256) void gemm_proj(const float* __restrict__ x,
                                                 const unsigned short* __restrict__ Wb,
                                                 float* __restrict__ proj) {
  __shared__ unsigned short Al[64][72];
  __shared__ unsigned short Bl[256][72];
  const int tid = threadIdx.x;
  const int lane = tid & 63;
  const int wv = tid >> 6;
  const int m0 = blockIdx.x * 64;
  const int nw0 = wv * 64;

  f32x4 acc[4][4];
#pragma unroll
  for (int m = 0; m < 4; ++m)
#pragma unroll
    for (int n = 0; n < 4; ++n) acc[m][n] = (f32x4){0.f, 0.f, 0.f, 0.f};

  const int arow = tid >> 2;
  const int akb = (tid & 3) * 16;

  for (int k0 = 0; k0 < D_SZ; k0 += 64) {
    {
      const float* src = &x[(size_t)(m0 + arow) * D_SZ + k0 + akb];
      unsigned tmp[8];
#pragma unroll
      for (int c = 0; c < 4; ++c) {
        const float4 f = *reinterpret_cast<const float4*>(src + c * 4);
        tmp[2 * c] = cvt2(f.x, f.y);
        tmp[2 * c + 1] = cvt2(f.z, f.w);
      }
      *reinterpret_cast<float4*>(&Al[arow][akb]) =
          *reinterpret_cast<const float4*>(&tmp[0]);
      *reinterpret_cast<float4*>(&Al[arow][akb + 8]) =
          *reinterpret_cast<const float4*>(&tmp[4]);
    }
    {
      const unsigned short* src = &Wb[(size_t)tid * D_SZ + k0];
#pragma unroll
      for (int h = 0; h < 8; ++h)
        *reinterpret_cast<float4*>(&Bl[tid][h * 8]) =
            *reinterpret_cast<const float4*>(&src[h * 8]);
    }
    __syncthreads();
    const int fr = lane & 15;
#pragma unroll
    for (int kk = 0; kk < 64; kk += 32) {
      const int kof = kk + (lane >> 4) * 8;
      bf16x8 af[4], bfr[4];
#pragma unroll
      for (int m = 0; m < 4; ++m)
        af[m] = *reinterpret_cast<const bf16x8*>(&Al[m * 16 + fr][kof]);
#pragma unroll
      for (int n = 0; n < 4; ++n)
        bfr[n] = *reinterpret_cast<const bf16x8*>(&Bl[nw0 + n * 16 + fr][kof]);
#pragma unroll
      for (int m = 0; m < 4; ++m)
#pragma unroll
        for (int n = 0; n < 4; ++n)
          acc[m][n] = __builtin_amdgcn_mfma_f32_16x16x32_bf16(
              af[m], bfr[n], acc[m][n], 0, 0, 0);
    }
    __syncthreads();
  }

  const int col = lane & 15;
  const int rb = (lane >> 4) * 4;
#pragma unroll
  for (int m = 0; m < 4; ++m)
#pragma unroll
    for (int n = 0; n < 4; ++n)
#pragma unroll
      for (int r = 0; r < 4; ++r)
        proj[(size_t)(m0 + m * 16 + rb + r) * NOUT + nw0 + n * 16 + col] =
            acc[m][n][r];
}

// ---------------------------------------------------------------------------
// Kernel 2: FUSED norm+gate+repack+gram (R17-verified, unchanged).
// ---------------------------------------------------------------------------
__global__ __launch_bounds__(512) void norm_gram(float* __restrict__ proj,
                                                 const float* __restrict__ b_gate,
                                                 float* __restrict__ gram) {
  const int u = threadIdx.x >> 6;        // 0..7 : step within block
  const int lane = threadIdx.x & 63;
  const int grp = blockIdx.x;            // b*NBLK + blk
  const int blk = grp & (NBLK - 1);
  const int b = grp >> 8;
  const int t0 = blk * U_BLK;
  const int m = (t0 + u) * B_SZ + b;

  __shared__ float lds_kn[U_BLK][64];    // 2 KB

  float* p = proj + (size_t)m * NOUT;
  const float kf = p[lane];
  const float vf = p[64 + lane];
  const float qf = p[128 + lane];
  const float gf = p[192 + lane];
  const float bg = b_gate[lane];
  const float ss = wave_red(kf * kf);
  const float kn = kf / (sqrtf(ss) + 1e-6f);
  const float dec = 1.f / (1.f + expf(-(gf + bg)));
  asm volatile("s_waitcnt vmcnt(0)" ::: "memory");
  float2* pp = reinterpret_cast<float2*>(p);
  float2 a; a.x = kn; a.y = qf;
  float2 c; c.x = vf; c.y = dec;
  pp[lane] = a;
  pp[64 + lane] = c;

  lds_kn[u][lane] = kn;
  __syncthreads();

  float row[8];
#pragma unroll
  for (int cc = 0; cc < 8; ++cc) {
    const float knc = lds_kn[cc][lane];
    const float lhs = (cc > u) ? kn : qf;
    row[cc] = wave_red(lhs * knc);
  }
  if (lane == 0) {
    float* dst = gram + ((size_t)grp * 64 + u * 8);
    float4 r0, r1;
    r0.x = row[0]; r0.y = row[1]; r0.z = row[2]; r0.w = row[3];
    r1.x = row[4]; r1.y = row[5]; r1.z = row[6]; r1.w = row[7];
    *reinterpret_cast<float4*>(dst) = r0;
    *reinterpret_cast<float4*>(dst + 4) = r1;
  }
}

// ---------------------------------------------------------------------------
// Kernel 3: scan — TWO chains per wave.  128 blocks x 4 waves; wave owns
// (b,i0),(b,i0+1).  Shared per-wave: staging (byte-identical macros), gram
// readlanes (CSE), bsrc/cvB B-fragments, knl.  Per-chain: A-fragment + 2
// MFMAs + recurrence; the two independent recurrences interleave (ILP).
// ---------------------------------------------------------------------------
__global__ __launch_bounds__(256, 1) void scan_kernel(
    const float* __restrict__ proj, const float* __restrict__ gram,
    const float* __restrict__ S0, float* __restrict__ out,
    float* __restrict__ Sfin) {
  const int wid = threadIdx.x >> 6;     // 0..3
  const int lane = threadIdx.x & 63;
  const int bid = blockIdx.x;           // 0..127
  const int b = (bid & 7) | ((bid >> 6) << 3);     // 8 blocks/b, same XCD
  const int ig = (bid >> 3) & 7;
  const int i0 = ig * 8 + wid * 2;
  const int i1 = i0 + 1;

  __shared__ float ldsT[2][64 * TSTR];   // transposed kn/q: [j][u | 8+u]
  __shared__ float ldsV[2][U_BLK * 128]; // row-major (v,dec) pairs
  __shared__ float ldsG[2][64];          // gram row
  __shared__ float ldsS[4][2][64];       // per-wave, per-chain S scratch

  float Sa = S0[(size_t)b * 4096 + i0 * 64 + lane];
  float Sb = S0[(size_t)b * 4096 + i1 * 64 + lane];

  const int r0 = wid * 2;           // this wave stages rows r0, r0+1
  float4 st0, st1;
  float stg = 0.f;

#define STAGE_LOAD(blkv)                                                      \
  {                                                                           \
    const size_t g0 = ((size_t)(((blkv) * U_BLK + r0) * B_SZ + b)) * NOUT;    \
    st0 = *reinterpret_cast<const float4*>(&proj[g0 + lane * 4]);             \
    st1 = *reinterpret_cast<const float4*>(&proj[g0 + (size_t)B_SZ * NOUT +   \
                                                 lane * 4]);                  \
    if (wid == 0) stg = gram[((size_t)b * NBLK + (blkv)) * 64 + lane];        \
  }

#define STAGE_WRITE(bufv)                                                     \
  {                                                                           \
    if (lane < 32) {                                                          \
      const int j0 = lane * 2;                                                \
      ldsT[bufv][j0 * TSTR + r0] = st0.x;                                     \
      ldsT[bufv][j0 * TSTR + 8 + r0] = st0.y;                                 \
      ldsT[bufv][(j0 + 1) * TSTR + r0] = st0.z;                               \
      ldsT[bufv][(j0 + 1) * TSTR + 8 + r0] = st0.w;                           \
      ldsT[bufv][j0 * TSTR + r0 + 1] = st1.x;                                 \
      ldsT[bufv][j0 * TSTR + 8 + r0 + 1] = st1.y;                             \
      ldsT[bufv][(j0 + 1) * TSTR + r0 + 1] = st1.z;                           \
      ldsT[bufv][(j0 + 1) * TSTR + 8 + r0 + 1] = st1.w;                       \
    } else {                                                                  \
      *reinterpret_cast<float4*>(                                             \
          &ldsV[bufv][r0 * 128 + (lane - 32) * 4]) = st0;                     \
      *reinterpret_cast<float4*>(                                             \
          &ldsV[bufv][(r0 + 1) * 128 + (lane - 32) * 4]) = st1;               \
    }                                                                         \
    if (wid == 0) ldsG[bufv][lane] = stg;                                     \
  }

#define GM(idx) __int_as_float(                                               \
    __builtin_amdgcn_readlane(__float_as_int(gv), (idx)))

  STAGE_LOAD(0)
  STAGE_WRITE(0)
  __syncthreads();

  const int koff = (lane >> 4) * 8;
  const int col = lane & 15;

  for (int blk = 0; blk < NBLK; ++blk) {
    const int buf = blk & 1;
    if (blk + 1 < NBLK) STAGE_LOAD(blk + 1)

    // ---- compute block blk, chains A (i0) and B (i1) ----
    ldsS[wid][0][lane] = Sa;
    ldsS[wid][1][lane] = Sb;
    asm volatile("s_waitcnt lgkmcnt(0)" ::: "memory");

    float2 vdvA[8], vdvB[8];
#pragma unroll
    for (int u = 0; u < 8; ++u) {
      vdvA[u] = *reinterpret_cast<const float2*>(&ldsV[buf][u * 128 + i0 * 2]);
      vdvB[u] = *reinterpret_cast<const float2*>(&ldsV[buf][u * 128 + i1 * 2]);
    }
    const float gv = ldsG[buf][lane];
    float knl[8];
#pragma unroll
    for (int w = 0; w < 8; ++w) knl[w] = ldsT[buf][lane * TSTR + w];

    // MFMA reductions: shared B-fragment, per-chain A-fragment
    f32x4 redA = (f32x4){0.f, 0.f, 0.f, 0.f};
    f32x4 redB = (f32x4){0.f, 0.f, 0.f, 0.f};
#pragma unroll
    for (int kk = 0; kk < 2; ++kk) {
      float aA[8], aB[8], bsrc[8];
      *reinterpret_cast<float4*>(&aA[0]) = *reinterpret_cast<const float4*>(
          &ldsS[wid][0][kk * 32 + koff]);
      *reinterpret_cast<float4*>(&aA[4]) = *reinterpret_cast<const float4*>(
          &ldsS[wid][0][kk * 32 + koff + 4]);
      *reinterpret_cast<float4*>(&aB[0]) = *reinterpret_cast<const float4*>(
          &ldsS[wid][1][kk * 32 + koff]);
      *reinterpret_cast<float4*>(&aB[4]) = *reinterpret_cast<const float4*>(
          &ldsS[wid][1][kk * 32 + koff + 4]);
#pragma unroll
      for (int t = 0; t < 8; ++t)
        bsrc[t] = ldsT[buf][(kk * 32 + koff + t) * TSTR + col];
      union { unsigned u[4]; bf16x8 v; } cvAa, cvAb, cvB;
#pragma unroll
      for (int h = 0; h < 4; ++h) {
        asm("v_cvt_pk_bf16_f32 %0, %1, %2"
            : "=v"(cvAa.u[h]) : "v"(aA[2 * h]), "v"(aA[2 * h + 1]));
        asm("v_cvt_pk_bf16_f32 %0, %1, %2"
            : "=v"(cvAb.u[h]) : "v"(aB[2 * h]), "v"(aB[2 * h + 1]));
        asm("v_cvt_pk_bf16_f32 %0, %1, %2"
            : "=v"(cvB.u[h]) : "v"(bsrc[2 * h]), "v"(bsrc[2 * h + 1]));
      }
      redA = __builtin_amdgcn_mfma_f32_16x16x32_bf16(cvAa.v, cvB.v, redA, 0, 0, 0);
      redB = __builtin_amdgcn_mfma_f32_16x16x32_bf16(cvAb.v, cvB.v, redB, 0, 0, 0);
    }

    // broadcast reductions
    float accA[8], sacA[8], accB[8], sacB[8];
    const int riA = __float_as_int(redA[0]);
    const int riB = __float_as_int(redB[0]);
#pragma unroll
    for (int u = 0; u < 8; ++u) {
      accA[u] = __int_as_float(__builtin_amdgcn_readlane(riA, u));
      sacA[u] = __int_as_float(__builtin_amdgcn_readlane(riA, 8 + u));
      accB[u] = __int_as_float(__builtin_amdgcn_readlane(riB, u));
      sacB[u] = __int_as_float(__builtin_amdgcn_readlane(riB, 8 + u));
    }

    // prefix products + reciprocals (per chain)
    float cA[9], rcA[8], cB[9], rcB[8];
    cA[0] = 1.f; cB[0] = 1.f;
#pragma unroll
    for (int u = 0; u < 8; ++u) {
      cA[u + 1] = cA[u] * vdvA[u].y;
      rcA[u] = __builtin_amdgcn_rcpf(cA[u + 1]);
      cB[u + 1] = cB[u] * vdvB[u].y;
      rcB[u] = __builtin_amdgcn_rcpf(cB[u + 1]);
    }

    // factored UT-transform recurrence, both chains (GM readlanes CSE)
    float dpA[8], sqvA[8], dpB[8], sqvB[8];
#pragma unroll
    for (int w = 0; w < 8; ++w) {
      const float gd = GM(w * 8 + w);
      const float dA = fmaf(-cA[w], accA[w], vdvA[w].x);
      dpA[w] = dA * rcA[w];
      sqvA[w] = fmaf(cA[w + 1], sacA[w], dA * gd);
      const float dB = fmaf(-cB[w], accB[w], vdvB[w].x);
      dpB[w] = dB * rcB[w];
      sqvB[w] = fmaf(cB[w + 1], sacB[w], dB * gd);
#pragma unroll
      for (int u = w + 1; u < 8; ++u) {
        const float gG = GM(w * 8 + u);
        const float gH = GM(u * 8 + w);
        accA[u] = fmaf(dpA[w], gG, accA[u]);
        sacA[u] = fmaf(dpA[w], gH, sacA[u]);
        accB[u] = fmaf(dpB[w], gG, accB[u]);
        sacB[u] = fmaf(dpB[w], gH, sacB[u]);
      }
    }
    float taccA = Sa, taccB = Sb;
#pragma unroll
    for (int w = 0; w < 8; ++w) {
      taccA = fmaf(dpA[w], knl[w], taccA);
      taccB = fmaf(dpB[w], knl[w], taccB);
    }
    Sa = cA[8] * taccA;
    Sb = cB[8] * taccB;

    // fused silu output: lanes 0..7 chain A, lanes 8..15 chain B
    if (lane < 16) {
      const float a0 = (lane & 1) ? sqvA[1] : sqvA[0];
      const float a1 = (lane & 1) ? sqvA[3] : sqvA[2];
      const float a2 = (lane & 1) ? sqvA[5] : sqvA[4];
      const float a3 = (lane & 1) ? sqvA[7] : sqvA[6];
      const float b0 = (lane & 2) ? a1 : a0;
      const float b1 = (lane & 2) ? a3 : a2;
      const float sA = (lane & 4) ? b1 : b0;
      const float e0 = (lane & 1) ? sqvB[1] : sqvB[0];
      const float e1 = (lane & 1) ? sqvB[3] : sqvB[2];
      const float e2 = (lane & 1) ? sqvB[5] : sqvB[4];
      const float e3 = (lane & 1) ? sqvB[7] : sqvB[6];
      const float f0 = (lane & 2) ? e1 : e0;
      const float f1 = (lane & 2) ? e3 : e2;
      const float sB = (lane & 4) ? f1 : f0;
      const float sq = (lane & 8) ? sB : sA;
      const int ii = i0 + ((lane >> 3) & 1);
      const size_t ob = (size_t)blk * U_BLK * (B_SZ * N_SZ) + b * N_SZ + ii;
      out[ob + (size_t)(lane & 7) * (B_SZ * N_SZ)] =
          sq * sq * __fdividef(1.f, 1.f + __expf(-sq));
    }
    // ---- end compute ----

    if (blk + 1 < NBLK) STAGE_WRITE(buf ^ 1)
    __syncthreads();
  }

  Sfin[(size_t)b * 4096 + i0 * 64 + lane] = Sa;
  Sfin[(size_t)b * 4096 + i1 * 64 + lane] = Sb;
#undef STAGE_LOAD
#undef STAGE_WRITE
#undef GM
}

// ---------------------------------------------------------------------------
extern "C" void kernel_launch(void* const* d_in, const int* in_sizes, int n_in,
                              void* d_out, int out_size, void* d_ws, size_t ws_size,
                              hipStream_t stream) {
  const float* x      = (const float*)d_in[0];
  const float* S0     = (const float*)d_in[1];
  const float* W      = (const float*)d_in[2];
  const float* b_gate = (const float*)d_in[3];
  float* out  = (float*)d_out;
  float* proj = (float*)d_ws;                                        // 33.55 MB
  float* gram = (float*)((char*)d_ws + (size_t)M_ROWS * NOUT * 4);   // +1 MB
  unsigned* Wb = (unsigned*)((char*)d_ws + 35u * 1024 * 1024);       // +0.5 MB

  hipLaunchKernelGGL(wcvt, dim3(256), dim3(256), 0, stream, W, Wb);
  hipLaunchKernelGGL(gemm_proj, dim3(M_ROWS / 64), dim3(256), 0, stream,
                     x, (const unsigned short*)Wb, proj);
  hipLaunchKernelGGL(norm_gram, dim3(B_SZ * NBLK), dim3(512), 0, stream,
                     proj, b_gate, gram);
  hipLaunchKernelGGL(scan_kernel, dim3(128), dim3(256), 0, stream,
                     proj, gram, S0, out, out + (size_t)T_STEPS * B_SZ * N_SZ);
}